// Round 11
// baseline (729.952 us; speedup 1.0000x reference)
//
#include <hip/hip_runtime.h>
#include <math.h>

// StyleLossW2 on MI355X. B=8, C=512, HW=16384. Output: 1 fp32 scalar.
// Round 11: convert with 4-deep batched loads (MLP); SYRK K-split 8 with
// decoupled last-block finish (threadfence+atomic counter, CUB-lookback
// pattern) -- covfin kernel eliminated, finish overlaps SYRK tail.
// tr(sqrt(G)) via degree-8 power-trace polynomial (host-fit coefficients).

typedef unsigned short u16;
typedef __bf16 bf16_t;
typedef bf16_t bf16x8 __attribute__((ext_vector_type(8)));
typedef float f32x4 __attribute__((ext_vector_type(4)));

#define EPSV 1e-4f
#define MS 262144   // 512*512
#define NUSAFE 1.35f

struct B9 { float v[9]; };

__device__ inline u16 f2b(float f) {
  bf16_t b = (bf16_t)f;
  return __builtin_bit_cast(u16, b);
}
__device__ inline float b2f(u16 u) {
  unsigned v = ((unsigned)u) << 16;
  return __builtin_bit_cast(float, v);
}

// ---------------- 2-phase double-buffered MFMA tile core --------------------
// (verified r2-r10: pre-swizzled global source + XOR'd ds_read -> 0 conflicts)
template <int FRM, int FRN, int LDA, int LDB, int SPS>
__device__ __forceinline__ void core2(const u16* A0, const u16* A1, const u16* A2,
                                      const u16* B0, const u16* B1, const u16* B2,
                                      int nsteps, u16* lds, f32x4 (&acc)[FRM][FRN],
                                      int wave, int lane) {
  const int TSA = FRM * 32 * 64;
  const int TSB = FRN * 32 * 64;
  const u16* As[3] = {A0, A1, A2};
  const u16* Bs[3] = {B0, B1, B2};
  int rr = lane & 15, g4 = lane >> 4, wm = wave >> 1, wn = wave & 1;
  int swz = (rr & 7) << 3;
#pragma unroll
  for (int it = 0; it < FRM; ++it) {
    int chunk = it * 4 + wave;
    __builtin_amdgcn_global_load_lds(
        (const __attribute__((address_space(1))) unsigned int*)(A0 + (size_t)(chunk * 8) * LDA),
        (__attribute__((address_space(3))) unsigned int*)&lds[chunk * 512], 16, 0, 0);
  }
#pragma unroll
  for (int it = 0; it < FRN; ++it) {
    int chunk = it * 4 + wave;
    __builtin_amdgcn_global_load_lds(
        (const __attribute__((address_space(1))) unsigned int*)(B0 + (size_t)(chunk * 8) * LDB),
        (__attribute__((address_space(3))) unsigned int*)&lds[TSA + chunk * 512], 16, 0, 0);
  }
  __syncthreads();
  int buf = 0;
  for (int ks = 0; ks < nsteps; ++ks) {
    if (ks + 1 < nsteps) {
      int kn = ks + 1;
      int seg = kn / SPS;
      int k0 = (kn % SPS) * 64;
      const u16* A = As[seg];
      const u16* B = Bs[seg];
      u16* dst = lds + (buf ^ 1) * (TSA + TSB);
#pragma unroll
      for (int it = 0; it < FRM; ++it) {
        int chunk = it * 4 + wave;
        __builtin_amdgcn_global_load_lds(
            (const __attribute__((address_space(1))) unsigned int*)(A + (size_t)(chunk * 8) * LDA + k0),
            (__attribute__((address_space(3))) unsigned int*)&dst[chunk * 512], 16, 0, 0);
      }
#pragma unroll
      for (int it = 0; it < FRN; ++it) {
        int chunk = it * 4 + wave;
        __builtin_amdgcn_global_load_lds(
            (const __attribute__((address_space(1))) unsigned int*)(B + (size_t)(chunk * 8) * LDB + k0),
            (__attribute__((address_space(3))) unsigned int*)&dst[TSA + chunk * 512], 16, 0, 0);
      }
    }
    const u16* lb = lds + buf * (TSA + TSB);
#pragma unroll
    for (int kk = 0; kk < 2; ++kk) {
      int ko = (kk * 32 + g4 * 8) ^ swz;
      bf16x8 af[FRM], bv[FRN];
#pragma unroll
      for (int m = 0; m < FRM; ++m)
        af[m] = *(const bf16x8*)&lb[(wm * FRM * 16 + m * 16 + rr) * 64 + ko];
#pragma unroll
      for (int n = 0; n < FRN; ++n)
        bv[n] = *(const bf16x8*)&lb[TSA + (wn * FRN * 16 + n * 16 + rr) * 64 + ko];
#pragma unroll
      for (int m = 0; m < FRM; ++m)
#pragma unroll
        for (int n = 0; n < FRN; ++n)
          acc[m][n] = __builtin_amdgcn_mfma_f32_16x16x32_bf16(af[m], bv[n],
                                                              acc[m][n], 0, 0, 0);
    }
    __syncthreads();
    buf ^= 1;
  }
}

// ---------------- convert fp32 -> bf16, batched loads; zero accumulators ----
__global__ __launch_bounds__(256) void k_convert(const float* __restrict__ X0,
                                                 const float* __restrict__ X1,
                                                 u16* __restrict__ Xh,
                                                 float* __restrict__ means,
                                                 float* __restrict__ trP,
                                                 int* __restrict__ cnt) {
  if (blockIdx.x == 0) {
    int t = threadIdx.x;
    if (t < 72) trP[t] = 0.0f;
    else if (t < 232) cnt[t - 72] = 0;
  }
  int wave = threadIdx.x >> 6, lane = threadIdx.x & 63;
  int r = blockIdx.x * 2 + (wave >> 1);   // 4096 blocks -> 8192 rows
  int half = wave & 1;
  const float* src = (r < 4096) ? X0 : X1;
  size_t off = (size_t)(r & 4095) * 16384 + half * 8192;
  const f32x4* s4 = (const f32x4*)(src + off);
  uint4* dst = (uint4*)(Xh + (size_t)r * 16384 + half * 8192);
  float sum = 0.0f;
#pragma unroll 2
  for (int i = 0; i < 8; ++i) {
    int c0 = (i * 2) * 64 + lane;
    int c1 = c0 + 64;
    f32x4 a0 = s4[2 * c0], b0 = s4[2 * c0 + 1];   // 4 independent 16B loads
    f32x4 a1 = s4[2 * c1], b1 = s4[2 * c1 + 1];
    sum += a0.x + a0.y + a0.z + a0.w + b0.x + b0.y + b0.z + b0.w;
    sum += a1.x + a1.y + a1.z + a1.w + b1.x + b1.y + b1.z + b1.w;
    uint4 o0, o1;
    o0.x = (unsigned)f2b(a0.x) | ((unsigned)f2b(a0.y) << 16);
    o0.y = (unsigned)f2b(a0.z) | ((unsigned)f2b(a0.w) << 16);
    o0.z = (unsigned)f2b(b0.x) | ((unsigned)f2b(b0.y) << 16);
    o0.w = (unsigned)f2b(b0.z) | ((unsigned)f2b(b0.w) << 16);
    o1.x = (unsigned)f2b(a1.x) | ((unsigned)f2b(a1.y) << 16);
    o1.y = (unsigned)f2b(a1.z) | ((unsigned)f2b(a1.w) << 16);
    o1.z = (unsigned)f2b(b1.x) | ((unsigned)f2b(b1.y) << 16);
    o1.w = (unsigned)f2b(b1.z) | ((unsigned)f2b(b1.w) << 16);
    dst[c0] = o0;
    dst[c1] = o1;
  }
  for (int o = 32; o; o >>= 1) sum += __shfl_down(sum, o);
  __shared__ float red[4];
  if (lane == 0) red[wave] = sum;
  __syncthreads();
  if (threadIdx.x == 0) {
    means[blockIdx.x * 2] = (red[0] + red[1]) * (1.0f / 16384.0f);
    means[blockIdx.x * 2 + 1] = (red[2] + red[3]) * (1.0f / 16384.0f);
  }
}

// ---- SYRK: 1280 jobs = 16 mats x 10 sym-tiles x 8 K-eighths, decoupled
//      finish: last block per tile sums partials, applies mean-outer + eps,
//      writes hi/lo bf16 (+ symmetric mirror) + diag ------------------------
__global__ __launch_bounds__(256) void k_syrk(const u16* __restrict__ Xh,
                                              float* __restrict__ covP,
                                              const float* __restrict__ means,
                                              float* __restrict__ covdiag,
                                              u16* __restrict__ Ch, u16* __restrict__ Cl,
                                              u16* __restrict__ TCh, u16* __restrict__ TCl,
                                              int* __restrict__ cnt) {
  const int TIv[10] = {0, 0, 0, 0, 1, 1, 1, 2, 2, 3};
  const int TJv[10] = {0, 1, 2, 3, 1, 2, 3, 2, 3, 3};
  int b = blockIdx.x;
  int sid = (b & 7) * 160 + (b >> 3);  // bijective XCD swizzle (1280 = 8*160)
  int mat = sid / 80, rem = sid % 80;
  int t = rem >> 3, q = rem & 7;       // q fastest: a tile's 8 blocks same XCD
  int ti = TIv[t], tj = TJv[t];
  int slot = mat * 10 + t;
  int tid = threadIdx.x, wave = tid >> 6, lane = tid & 63;
  __shared__ u16 lds[2 * 2 * 128 * 64];  // 64 KB
  f32x4 acc[4][4] = {};
  int srow = lane >> 3;
  int scol = ((lane & 7) * 8) ^ (srow << 3);
  const u16* base = Xh + (size_t)mat * 512 * 16384 + (size_t)q * 2048;
  const u16* Ab = base + (size_t)(ti * 128 + srow) * 16384 + scol;
  const u16* Bb = base + (size_t)(tj * 128 + srow) * 16384 + scol;
  core2<4, 4, 16384, 16384, 64>(Ab, Ab, Ab, Bb, Bb, Bb, 32, lds, acc, wave, lane);
  int wm = wave >> 1, wn = wave & 1, rr = lane & 15, g4 = lane >> 4;
  // partial store, tile-local [128][128]
  float* Pw = covP + ((size_t)slot * 8 + q) * 16384;
#pragma unroll
  for (int m = 0; m < 4; ++m)
#pragma unroll
    for (int n = 0; n < 4; ++n) {
      int lr = wm * 64 + m * 16 + g4 * 4;
      int lc = wn * 64 + n * 16 + rr;
      Pw[(lr + 0) * 128 + lc] = acc[m][n][0];
      Pw[(lr + 1) * 128 + lc] = acc[m][n][1];
      Pw[(lr + 2) * 128 + lc] = acc[m][n][2];
      Pw[(lr + 3) * 128 + lc] = acc[m][n][3];
    }
  // decoupled finish (release: fence then count; acquire: fence then read)
  __threadfence();
  __syncthreads();
  __shared__ int lastFlag;
  if (tid == 0) lastFlag = (atomicAdd(&cnt[slot], 1) == 7);
  __syncthreads();
  if (!lastFlag) return;
  __threadfence();
  const float* P = covP + (size_t)slot * 8 * 16384;
  u16* H = (mat < 8 ? Ch : TCh) + (size_t)(mat & 7) * MS;
  u16* L = (mat < 8 ? Cl : TCl) + (size_t)(mat & 7) * MS;
  const float* mA = means + mat * 512;
  for (int i4 = tid; i4 < 4096; i4 += 256) {
    int r = i4 >> 5, cb = (i4 & 31) * 4;
    const float* p0 = P + r * 128 + cb;
    float4 v0 = *(const float4*)p0;
    float vv[4] = {v0.x, v0.y, v0.z, v0.w};
#pragma unroll
    for (int q2 = 1; q2 < 8; ++q2) {
      float4 a = *(const float4*)(p0 + q2 * 16384);
      vv[0] += a.x; vv[1] += a.y; vv[2] += a.z; vv[3] += a.w;
    }
    int gr = ti * 128 + r;
    int gc0 = tj * 128 + cb;
    float mr = mA[gr];
    ushort4 h4, l4;
    unsigned short* ph = &h4.x;
    unsigned short* pl = &l4.x;
#pragma unroll
    for (int k = 0; k < 4; ++k) {
      float x = vv[k] * (1.0f / 16384.0f) - mr * mA[gc0 + k];
      if (gr == gc0 + k) {
        x += EPSV;
        covdiag[mat * 512 + gr] = x;
      }
      u16 hh = f2b(x);
      ph[k] = hh;
      pl[k] = f2b(x - b2f(hh));
    }
    *(ushort4*)&H[(size_t)gr * 512 + gc0] = h4;
    *(ushort4*)&L[(size_t)gr * 512 + gc0] = l4;
    if (ti != tj) {  // symmetric mirror
#pragma unroll
      for (int k = 0; k < 4; ++k) {
        H[(size_t)(gc0 + k) * 512 + gr] = ph[k];
        L[(size_t)(gc0 + k) * 512 + gr] = pl[k];
      }
    }
  }
}

// ---------------- power GEMM, 64x64 tiles -----------------------------------
struct GJ {
  const u16 *Ah, *Al, *Bh, *Bl;   // B arrays are transposed-layout operands
  u16 *oH, *oL, *oTH, *oTL;
  const float* trP;
  float* tr1A; float* tr2A;
  float c0;
  int nupow;
};

__global__ __launch_bounds__(256) void k_gg(GJ p, GJ q, int split) {
  int sid = ((blockIdx.x & 7) * (gridDim.x >> 3)) + (blockIdx.x >> 3);
  const GJ j = (sid < split) ? p : q;
  int blk = (sid < split) ? sid : sid - split;
  int mat = blk >> 6, tile = blk & 63;
  int ti = tile >> 3, tj = tile & 7;
  int tid = threadIdx.x, wave = tid >> 6, lane = tid & 63;
  __shared__ u16 lds[2 * 2 * 64 * 64];  // 32 KB
  f32x4 acc[2][2] = {};
  int srow = lane >> 3;
  int scol = ((lane & 7) * 8) ^ (srow << 3);
  size_t mo = (size_t)mat * MS;
  size_t ao = mo + (size_t)(ti * 64 + srow) * 512 + scol;
  size_t bo = mo + (size_t)(tj * 64 + srow) * 512 + scol;
  const u16* A0 = j.Ah + ao;
  const u16* A2 = j.Al + ao;
  const u16* B0 = j.Bh + bo;
  const u16* B1 = j.Bl + bo;
  core2<2, 2, 512, 512, 8>(A0, A0, A2, B0, B1, B0, 24, lds, acc, wave, lane);
  int wm = wave >> 1, wn = wave & 1, rr = lane & 15, g4 = lane >> 4;
  float c0 = j.c0;
  if (j.nupow) {
    float inv = j.trP[mat] / (NUSAFE * j.trP[8 + mat]);  // 1/nu
    c0 *= inv;
    if (j.nupow == 2) c0 *= inv;
  }
  float fro = 0.0f, dsum = 0.0f;
#pragma unroll
  for (int m = 0; m < 2; ++m)
#pragma unroll
    for (int n = 0; n < 2; ++n) {
      int rowb = ti * 64 + wm * 32 + m * 16 + g4 * 4;
      int col = tj * 64 + wn * 32 + n * 16 + rr;
      ushort4 h4, l4;
      unsigned short* ph = &h4.x;
      unsigned short* pl = &l4.x;
#pragma unroll
      for (int v4 = 0; v4 < 4; ++v4) {
        float vv = c0 * acc[m][n][v4];
        u16 hh = f2b(vv);
        ph[v4] = hh;
        pl[v4] = f2b(vv - b2f(hh));
        if (j.tr2A) {
          fro += vv * vv;
          if ((rowb + v4) == col) dsum += vv;
        }
        j.oH[mo + (size_t)(rowb + v4) * 512 + col] = hh;
        j.oL[mo + (size_t)(rowb + v4) * 512 + col] = pl[v4];
      }
      *(ushort4*)&j.oTH[mo + (size_t)col * 512 + rowb] = h4;
      *(ushort4*)&j.oTL[mo + (size_t)col * 512 + rowb] = l4;
    }
  if (j.tr2A) {
    for (int o = 32; o; o >>= 1) {
      fro += __shfl_down(fro, o);
      dsum += __shfl_down(dsum, o);
    }
    if (lane == 0) {
      atomicAdd(&j.tr2A[mat], fro);
      if (ti == tj) atomicAdd(&j.tr1A[mat], dsum);
    }
  }
}

// ---------------- transpose-dots: tau_{p+2} = <A_p, B_p^T> ------------------
__global__ __launch_bounds__(256) void k_dots(const u16* __restrict__ U0,
                                              float* __restrict__ tau) {
  const int PA[7] = {0, 4, 4, 8, 8, 12, 12};
  const int PB[7] = {2, 2, 6, 6, 10, 10, 14};
  int b = blockIdx.x;           // 224 = 7 pairs x 8 mats x 4 chunks
  int pair = b / 32;
  int rem = b & 31;
  int mat = rem >> 2, chunk = rem & 3;
  const size_t AS = 8ull * MS;
  size_t off = (size_t)mat * MS + (size_t)chunk * 65536;
  const ushort4* Ah = (const ushort4*)(U0 + (size_t)PA[pair] * AS + off);
  const ushort4* Al = (const ushort4*)(U0 + (size_t)(PA[pair] + 1) * AS + off);
  const ushort4* Bh = (const ushort4*)(U0 + (size_t)PB[pair] * AS + off);
  const ushort4* Bl = (const ushort4*)(U0 + (size_t)(PB[pair] + 1) * AS + off);
  float s = 0.0f;
  for (int i = threadIdx.x; i < 16384; i += 256) {
    ushort4 ah = Ah[i], al = Al[i], bh = Bh[i], bl = Bl[i];
    s += (b2f(ah.x) + b2f(al.x)) * (b2f(bh.x) + b2f(bl.x));
    s += (b2f(ah.y) + b2f(al.y)) * (b2f(bh.y) + b2f(bl.y));
    s += (b2f(ah.z) + b2f(al.z)) * (b2f(bh.z) + b2f(bl.z));
    s += (b2f(ah.w) + b2f(al.w)) * (b2f(bh.w) + b2f(bl.w));
  }
  for (int o = 32; o; o >>= 1) s += __shfl_down(s, o);
  __shared__ float red[4];
  if ((threadIdx.x & 63) == 0) red[threadIdx.x >> 6] = s;
  __syncthreads();
  if (threadIdx.x == 0)
    atomicAdd(&tau[pair * 8 + mat], red[0] + red[1] + red[2] + red[3]);
}

// ---------------- final scalar ----------------------------------------------
__global__ __launch_bounds__(256) void k_final(const float* __restrict__ trP,
                                               const float* __restrict__ covdiag,
                                               const float* __restrict__ means,
                                               B9 B, float* __restrict__ out) {
  float s = 0.0f;
  for (int i = threadIdx.x; i < 4096; i += 256) {
    float dm = means[i] - means[4096 + i];
    s += dm * dm;
  }
  for (int i = threadIdx.x; i < 8192; i += 256) s += covdiag[i];
  if (threadIdx.x < 8) {
    int m = threadIdx.x;
    float t1 = trP[m], t2 = trP[8 + m];
    float nu = NUSAFE * t2 / t1;
    float inv = 1.0f / nu;
    float tau[9];
    tau[0] = 512.0f;
    tau[1] = t1 * inv;
    float sc[7] = {inv * inv, inv, 1.f, 1.f, 1.f, 1.f, 1.f};
#pragma unroll
    for (int p = 0; p < 7; ++p) tau[p + 2] = trP[16 + p * 8 + m] * sc[p];
    float tp = 0.0f;
#pragma unroll
    for (int k = 0; k < 9; ++k) tp += B.v[k] * tau[k];
    s -= 2.0f * sqrtf(nu) * tp;
  }
  for (int o = 32; o; o >>= 1) s += __shfl_down(s, o);
  __shared__ float red[4];
  if ((threadIdx.x & 63) == 0) red[threadIdx.x >> 6] = s;
  __syncthreads();
  if (threadIdx.x == 0)
    out[0] = (red[0] + red[1] + red[2] + red[3]) * (1.0f / 4096.0f);
}

// ---------------- host: degree-8 Chebyshev fit of sqrt on [0.2,1.4] --------
static void fit_sqrt_coeffs(B9* out) {
  const int D = 8, N = 64;
  double a[D + 1];
  for (int n = 0; n <= D; ++n) {
    double s = 0.0;
    for (int m = 0; m < N; ++m) {
      double th = M_PI * (m + 0.5) / N;
      double x = 0.8 + 0.6 * cos(th);
      s += sqrt(x) * cos(n * th);
    }
    a[n] = 2.0 * s / N;
  }
  a[0] *= 0.5;
  double c[D + 1] = {0}, Tm[D + 1] = {0}, Tc[D + 1] = {0}, Tn[D + 1];
  Tm[0] = 1.0; c[0] += a[0];
  Tc[1] = 1.0; c[1] += a[1];
  for (int n = 2; n <= D; ++n) {
    for (int k = 0; k <= D; ++k) Tn[k] = -Tm[k];
    for (int k = 1; k <= D; ++k) Tn[k] += 2.0 * Tc[k - 1];
    for (int k = 0; k <= D; ++k) { c[k] += a[n] * Tn[k]; Tm[k] = Tc[k]; Tc[k] = Tn[k]; }
  }
  double b[D + 1] = {0};
  for (int k = 0; k <= D; ++k) {
    double inv6k = pow(1.0 / 0.6, k);
    double binom = 1.0;
    for (int jj = 0; jj <= k; ++jj) {
      b[jj] += c[k] * inv6k * binom * pow(-0.8, k - jj);
      binom = binom * (double)(k - jj) / (double)(jj + 1);
    }
  }
  for (int jj = 0; jj <= D; ++jj) out->v[jj] = (float)b[jj];
}

// ---------------- host ------------------------------------------------------
extern "C" void kernel_launch(void* const* d_in, const int* in_sizes, int n_in,
                              void* d_out, int out_size, void* d_ws, size_t ws_size,
                              hipStream_t stream) {
  (void)in_sizes; (void)n_in; (void)out_size; (void)ws_size;
  const float* X0 = (const float*)d_in[0];
  const float* X1 = (const float*)d_in[1];
  float* out = (float*)d_out;

  B9 B;
  fit_sqrt_coeffs(&B);

  char* w = (char*)d_ws;
  auto carve = [&](size_t bytes) -> void* {
    void* r = (void*)w;
    w += (bytes + 255) & ~(size_t)255;
    return r;
  };
  u16*   Xh   = (u16*)carve(2ull * 8 * 512 * 16384 * 2);   // 256 MiB
  float* covP = (float*)carve(8ull * 160 * 16384 * 4);     // 80 MiB partials
  u16* Ch  = (u16*)carve(8 * MS * 2); u16* Cl  = (u16*)carve(8 * MS * 2);
  u16* TCh = (u16*)carve(8 * MS * 2); u16* TCl = (u16*)carve(8 * MS * 2);
  float* covdiag = (float*)carve(16 * 512 * 4);
  float* means = (float*)carve(8192 * 4);
  float* trP   = (float*)carve(128 * 4);  // tr1[8], fro2[8], tau[7][8]
  int*   cnt   = (int*)carve(160 * 4);

  // Power arrays (4 MiB units) alias covP (dead after SYRK finish): 16 units.
  const size_t AS = 8ull * MS;
  u16* U0 = (u16*)covP;
  auto unit = [&](int i) -> u16* { return U0 + (size_t)i * AS; };
  u16 *U1h = unit(0), *U1l = unit(1), *U1th = unit(2), *U1tl = unit(3);
  u16 *U2h = unit(4), *U2l = unit(5), *U2th = unit(6), *U2tl = unit(7);
  u16 *U3h = unit(8), *U3l = unit(9), *U3th = unit(10), *U3tl = unit(11);
  u16 *U4h = unit(12), *U4l = unit(13), *U4th = unit(14), *U4tl = unit(15);

  // 1) fp32 -> bf16 + means (+ zero trP, cnt)
  k_convert<<<4096, 256, 0, stream>>>(X0, X1, Xh, means, trP, cnt);

  // 2) SYRK (K-split 8) with decoupled finish -> Ch/Cl/TCh/TCl + covdiag
  k_syrk<<<1280, 256, 0, stream>>>(Xh, covP, means, covdiag,
                                   Ch, Cl, TCh, TCl, cnt);

  // 3) U1 = G = C @ TC (TC symmetric) + moments (tr G, ||G||_F^2)
  {
    GJ gj = {Ch, Cl, TCh, TCl, U1h, U1l, U1th, U1tl,
             nullptr, trP, trP + 8, 1.0f, 0};
    k_gg<<<512, 256, 0, stream>>>(gj, gj, 512);
  }
  // 4) U2 = Ghat^2 = (G @ G) / nu^2
  {
    GJ pj = {U1h, U1l, U1th, U1tl, U2h, U2l, U2th, U2tl,
             trP, nullptr, nullptr, 1.0f, 2};
    k_gg<<<512, 256, 0, stream>>>(pj, pj, 512);
  }
  // 5) U3 = Ghat^3 = (Ghat^2 @ G)/nu ; U4 = Ghat^4 = Ghat^2 @ Ghat^2
  {
    GJ p3 = {U2h, U2l, U1th, U1tl, U3h, U3l, U3th, U3tl,
             trP, nullptr, nullptr, 1.0f, 1};
    GJ p4 = {U2h, U2l, U2th, U2tl, U4h, U4l, U4th, U4tl,
             trP, nullptr, nullptr, 1.0f, 0};
    k_gg<<<1024, 256, 0, stream>>>(p3, p4, 512);
  }
  // 6) transpose-dots -> tau_2..tau_8
  k_dots<<<224, 256, 0, stream>>>(U0, trP + 16);

  // 7) loss
  k_final<<<1, 256, 0, stream>>>(trP, covdiag, means, B, out);
}

// Round 12
// 434.743 us; speedup vs baseline: 1.6790x; 1.6790x over previous
//
#include <hip/hip_runtime.h>
#include <math.h>

// StyleLossW2 on MI355X. B=8, C=512, HW=16384. Output: 1 fp32 scalar.
// Round 12: r10 structure (SYRK K-split 4 + covfin kernel; decoupled-finish
// REVERTED -- threadfence L2-writeback serialized r11's SYRK 140->470us)
// + r11's 4-deep batched-load convert. Power-trace polynomial for tr(sqrt(G)).

typedef unsigned short u16;
typedef __bf16 bf16_t;
typedef bf16_t bf16x8 __attribute__((ext_vector_type(8)));
typedef float f32x4 __attribute__((ext_vector_type(4)));

#define EPSV 1e-4f
#define MS 262144   // 512*512
#define NUSAFE 1.35f

struct B9 { float v[9]; };

__device__ inline u16 f2b(float f) {
  bf16_t b = (bf16_t)f;
  return __builtin_bit_cast(u16, b);
}
__device__ inline float b2f(u16 u) {
  unsigned v = ((unsigned)u) << 16;
  return __builtin_bit_cast(float, v);
}

// ---------------- 2-phase double-buffered MFMA tile core --------------------
// (verified r2-r10: pre-swizzled global source + XOR'd ds_read -> 0 conflicts)
template <int FRM, int FRN, int LDA, int LDB, int SPS>
__device__ __forceinline__ void core2(const u16* A0, const u16* A1, const u16* A2,
                                      const u16* B0, const u16* B1, const u16* B2,
                                      int nsteps, u16* lds, f32x4 (&acc)[FRM][FRN],
                                      int wave, int lane) {
  const int TSA = FRM * 32 * 64;
  const int TSB = FRN * 32 * 64;
  const u16* As[3] = {A0, A1, A2};
  const u16* Bs[3] = {B0, B1, B2};
  int rr = lane & 15, g4 = lane >> 4, wm = wave >> 1, wn = wave & 1;
  int swz = (rr & 7) << 3;
#pragma unroll
  for (int it = 0; it < FRM; ++it) {
    int chunk = it * 4 + wave;
    __builtin_amdgcn_global_load_lds(
        (const __attribute__((address_space(1))) unsigned int*)(A0 + (size_t)(chunk * 8) * LDA),
        (__attribute__((address_space(3))) unsigned int*)&lds[chunk * 512], 16, 0, 0);
  }
#pragma unroll
  for (int it = 0; it < FRN; ++it) {
    int chunk = it * 4 + wave;
    __builtin_amdgcn_global_load_lds(
        (const __attribute__((address_space(1))) unsigned int*)(B0 + (size_t)(chunk * 8) * LDB),
        (__attribute__((address_space(3))) unsigned int*)&lds[TSA + chunk * 512], 16, 0, 0);
  }
  __syncthreads();
  int buf = 0;
  for (int ks = 0; ks < nsteps; ++ks) {
    if (ks + 1 < nsteps) {
      int kn = ks + 1;
      int seg = kn / SPS;
      int k0 = (kn % SPS) * 64;
      const u16* A = As[seg];
      const u16* B = Bs[seg];
      u16* dst = lds + (buf ^ 1) * (TSA + TSB);
#pragma unroll
      for (int it = 0; it < FRM; ++it) {
        int chunk = it * 4 + wave;
        __builtin_amdgcn_global_load_lds(
            (const __attribute__((address_space(1))) unsigned int*)(A + (size_t)(chunk * 8) * LDA + k0),
            (__attribute__((address_space(3))) unsigned int*)&dst[chunk * 512], 16, 0, 0);
      }
#pragma unroll
      for (int it = 0; it < FRN; ++it) {
        int chunk = it * 4 + wave;
        __builtin_amdgcn_global_load_lds(
            (const __attribute__((address_space(1))) unsigned int*)(B + (size_t)(chunk * 8) * LDB + k0),
            (__attribute__((address_space(3))) unsigned int*)&dst[TSA + chunk * 512], 16, 0, 0);
      }
    }
    const u16* lb = lds + buf * (TSA + TSB);
#pragma unroll
    for (int kk = 0; kk < 2; ++kk) {
      int ko = (kk * 32 + g4 * 8) ^ swz;
      bf16x8 af[FRM], bv[FRN];
#pragma unroll
      for (int m = 0; m < FRM; ++m)
        af[m] = *(const bf16x8*)&lb[(wm * FRM * 16 + m * 16 + rr) * 64 + ko];
#pragma unroll
      for (int n = 0; n < FRN; ++n)
        bv[n] = *(const bf16x8*)&lb[TSA + (wn * FRN * 16 + n * 16 + rr) * 64 + ko];
#pragma unroll
      for (int m = 0; m < FRM; ++m)
#pragma unroll
        for (int n = 0; n < FRN; ++n)
          acc[m][n] = __builtin_amdgcn_mfma_f32_16x16x32_bf16(af[m], bv[n],
                                                              acc[m][n], 0, 0, 0);
    }
    __syncthreads();
    buf ^= 1;
  }
}

// ---------------- convert fp32 -> bf16, 4-deep batched loads ----------------
__global__ __launch_bounds__(256) void k_convert(const float* __restrict__ X0,
                                                 const float* __restrict__ X1,
                                                 u16* __restrict__ Xh,
                                                 float* __restrict__ means) {
  int wave = threadIdx.x >> 6, lane = threadIdx.x & 63;
  int r = blockIdx.x * 2 + (wave >> 1);   // 4096 blocks -> 8192 rows
  int half = wave & 1;
  const float* src = (r < 4096) ? X0 : X1;
  size_t off = (size_t)(r & 4095) * 16384 + half * 8192;
  const f32x4* s4 = (const f32x4*)(src + off);
  uint4* dst = (uint4*)(Xh + (size_t)r * 16384 + half * 8192);
  float sum = 0.0f;
#pragma unroll 2
  for (int i = 0; i < 8; ++i) {
    int c0 = (i * 2) * 64 + lane;
    int c1 = c0 + 64;
    f32x4 a0 = s4[2 * c0], b0 = s4[2 * c0 + 1];   // 4 independent 16B loads
    f32x4 a1 = s4[2 * c1], b1 = s4[2 * c1 + 1];
    sum += a0.x + a0.y + a0.z + a0.w + b0.x + b0.y + b0.z + b0.w;
    sum += a1.x + a1.y + a1.z + a1.w + b1.x + b1.y + b1.z + b1.w;
    uint4 o0, o1;
    o0.x = (unsigned)f2b(a0.x) | ((unsigned)f2b(a0.y) << 16);
    o0.y = (unsigned)f2b(a0.z) | ((unsigned)f2b(a0.w) << 16);
    o0.z = (unsigned)f2b(b0.x) | ((unsigned)f2b(b0.y) << 16);
    o0.w = (unsigned)f2b(b0.z) | ((unsigned)f2b(b0.w) << 16);
    o1.x = (unsigned)f2b(a1.x) | ((unsigned)f2b(a1.y) << 16);
    o1.y = (unsigned)f2b(a1.z) | ((unsigned)f2b(a1.w) << 16);
    o1.z = (unsigned)f2b(b1.x) | ((unsigned)f2b(b1.y) << 16);
    o1.w = (unsigned)f2b(b1.z) | ((unsigned)f2b(b1.w) << 16);
    dst[c0] = o0;
    dst[c1] = o1;
  }
  for (int o = 32; o; o >>= 1) sum += __shfl_down(sum, o);
  __shared__ float red[4];
  if (lane == 0) red[wave] = sum;
  __syncthreads();
  if (threadIdx.x == 0) {
    means[blockIdx.x * 2] = (red[0] + red[1]) * (1.0f / 16384.0f);
    means[blockIdx.x * 2 + 1] = (red[2] + red[3]) * (1.0f / 16384.0f);
  }
}

// ---------------- SYRK: 640 jobs = 16 mats x 10 sym-tiles x 4 K-quarters ----
__global__ __launch_bounds__(256) void k_syrk(const u16* __restrict__ Xh,
                                              float* __restrict__ covP) {
  const int TIv[10] = {0, 0, 0, 0, 1, 1, 1, 2, 2, 3};
  const int TJv[10] = {0, 1, 2, 3, 1, 2, 3, 2, 3, 3};
  int b = blockIdx.x;
  int sid = (b & 7) * 80 + (b >> 3);  // bijective XCD swizzle
  int mat = sid / 40, rem = sid % 40;
  int t = rem >> 2, q = rem & 3;
  int ti = TIv[t], tj = TJv[t];
  int tid = threadIdx.x, wave = tid >> 6, lane = tid & 63;
  __shared__ u16 lds[2 * 2 * 128 * 64];  // 64 KB
  f32x4 acc[4][4] = {};
  int srow = lane >> 3;
  int scol = ((lane & 7) * 8) ^ (srow << 3);
  const u16* base = Xh + (size_t)mat * 512 * 16384 + (size_t)q * 4096;
  const u16* Ab = base + (size_t)(ti * 128 + srow) * 16384 + scol;
  const u16* Bb = base + (size_t)(tj * 128 + srow) * 16384 + scol;
  core2<4, 4, 16384, 16384, 64>(Ab, Ab, Ab, Bb, Bb, Bb, 64, lds, acc, wave, lane);
  int wm = wave >> 1, wn = wave & 1, rr = lane & 15, g4 = lane >> 4;
  float* out = covP + ((size_t)q * 16 + mat) * MS;
#pragma unroll
  for (int m = 0; m < 4; ++m)
#pragma unroll
    for (int n = 0; n < 4; ++n) {
      int rowb = ti * 128 + wm * 64 + m * 16 + g4 * 4;
      int col = tj * 128 + wn * 64 + n * 16 + rr;
      float v0 = acc[m][n][0], v1 = acc[m][n][1], v2 = acc[m][n][2], v3 = acc[m][n][3];
      out[(size_t)(rowb + 0) * 512 + col] = v0;
      out[(size_t)(rowb + 1) * 512 + col] = v1;
      out[(size_t)(rowb + 2) * 512 + col] = v2;
      out[(size_t)(rowb + 3) * 512 + col] = v3;
      if (ti != tj) {
        float4 tv = {v0, v1, v2, v3};
        *(float4*)&out[(size_t)col * 512 + rowb] = tv;
      }
    }
}

// ---- cov finish: sum 4 K-quarters, /HW - mean outer + eps I ->
//      hi/lo bf16 (C 0-7, TC 8-15) + fp32 diag; zero trP[0..71] -------------
__global__ __launch_bounds__(256) void k_covfin2(const float* __restrict__ covP,
                                                 const float* __restrict__ means,
                                                 float* __restrict__ covdiag,
                                                 float* __restrict__ trP,
                                                 u16* __restrict__ Ch, u16* __restrict__ Cl,
                                                 u16* __restrict__ TCh, u16* __restrict__ TCl) {
  if (blockIdx.x == 0 && threadIdx.x < 72) trP[threadIdx.x] = 0.0f;
  const int NF4 = 16 * MS / 4;
  const float4* P = (const float4*)covP;
  for (int i4 = blockIdx.x * 256 + threadIdx.x; i4 < NF4; i4 += gridDim.x * 256) {
    float4 v0 = P[i4];
    float v[4] = {v0.x, v0.y, v0.z, v0.w};
#pragma unroll
    for (int k = 1; k < 4; ++k) {
      float4 a = P[(size_t)k * NF4 + i4];
      v[0] += a.x; v[1] += a.y; v[2] += a.z; v[3] += a.w;
    }
    int mat = i4 >> 16;
    int r = (i4 >> 7) & 511;
    int cb = (i4 & 127) * 4;
    float mr = means[mat * 512 + r];
    ushort4 h4, l4;
    unsigned short* ph = &h4.x;
    unsigned short* pl = &l4.x;
#pragma unroll
    for (int t = 0; t < 4; ++t) {
      float vv = v[t] * (1.0f / 16384.0f) - mr * means[mat * 512 + cb + t];
      if (r == cb + t) {
        vv += EPSV;
        covdiag[mat * 512 + r] = vv;
      }
      u16 hh = f2b(vv);
      ph[t] = hh;
      pl[t] = f2b(vv - b2f(hh));
    }
    int half = (mat >= 8);
    int loc4 = i4 - half * (NF4 / 2);
    ((ushort4*)(half ? TCh : Ch))[loc4] = h4;
    ((ushort4*)(half ? TCl : Cl))[loc4] = l4;
  }
}

// ---------------- power GEMM, 64x64 tiles -----------------------------------
struct GJ {
  const u16 *Ah, *Al, *Bh, *Bl;   // B arrays are transposed-layout operands
  u16 *oH, *oL, *oTH, *oTL;
  const float* trP;
  float* tr1A; float* tr2A;
  float c0;
  int nupow;
};

__global__ __launch_bounds__(256) void k_gg(GJ p, GJ q, int split) {
  int sid = ((blockIdx.x & 7) * (gridDim.x >> 3)) + (blockIdx.x >> 3);
  const GJ j = (sid < split) ? p : q;
  int blk = (sid < split) ? sid : sid - split;
  int mat = blk >> 6, tile = blk & 63;
  int ti = tile >> 3, tj = tile & 7;
  int tid = threadIdx.x, wave = tid >> 6, lane = tid & 63;
  __shared__ u16 lds[2 * 2 * 64 * 64];  // 32 KB
  f32x4 acc[2][2] = {};
  int srow = lane >> 3;
  int scol = ((lane & 7) * 8) ^ (srow << 3);
  size_t mo = (size_t)mat * MS;
  size_t ao = mo + (size_t)(ti * 64 + srow) * 512 + scol;
  size_t bo = mo + (size_t)(tj * 64 + srow) * 512 + scol;
  const u16* A0 = j.Ah + ao;
  const u16* A2 = j.Al + ao;
  const u16* B0 = j.Bh + bo;
  const u16* B1 = j.Bl + bo;
  core2<2, 2, 512, 512, 8>(A0, A0, A2, B0, B1, B0, 24, lds, acc, wave, lane);
  int wm = wave >> 1, wn = wave & 1, rr = lane & 15, g4 = lane >> 4;
  float c0 = j.c0;
  if (j.nupow) {
    float inv = j.trP[mat] / (NUSAFE * j.trP[8 + mat]);  // 1/nu
    c0 *= inv;
    if (j.nupow == 2) c0 *= inv;
  }
  float fro = 0.0f, dsum = 0.0f;
#pragma unroll
  for (int m = 0; m < 2; ++m)
#pragma unroll
    for (int n = 0; n < 2; ++n) {
      int rowb = ti * 64 + wm * 32 + m * 16 + g4 * 4;
      int col = tj * 64 + wn * 32 + n * 16 + rr;
      ushort4 h4, l4;
      unsigned short* ph = &h4.x;
      unsigned short* pl = &l4.x;
#pragma unroll
      for (int v4 = 0; v4 < 4; ++v4) {
        float vv = c0 * acc[m][n][v4];
        u16 hh = f2b(vv);
        ph[v4] = hh;
        pl[v4] = f2b(vv - b2f(hh));
        if (j.tr2A) {
          fro += vv * vv;
          if ((rowb + v4) == col) dsum += vv;
        }
        j.oH[mo + (size_t)(rowb + v4) * 512 + col] = hh;
        j.oL[mo + (size_t)(rowb + v4) * 512 + col] = pl[v4];
      }
      *(ushort4*)&j.oTH[mo + (size_t)col * 512 + rowb] = h4;
      *(ushort4*)&j.oTL[mo + (size_t)col * 512 + rowb] = l4;
    }
  if (j.tr2A) {
    for (int o = 32; o; o >>= 1) {
      fro += __shfl_down(fro, o);
      dsum += __shfl_down(dsum, o);
    }
    if (lane == 0) {
      atomicAdd(&j.tr2A[mat], fro);
      if (ti == tj) atomicAdd(&j.tr1A[mat], dsum);
    }
  }
}

// ---------------- transpose-dots: tau_{p+2} = <A_p, B_p^T> ------------------
__global__ __launch_bounds__(256) void k_dots(const u16* __restrict__ U0,
                                              float* __restrict__ tau) {
  const int PA[7] = {0, 4, 4, 8, 8, 12, 12};
  const int PB[7] = {2, 2, 6, 6, 10, 10, 14};
  int b = blockIdx.x;           // 224 = 7 pairs x 8 mats x 4 chunks
  int pair = b / 32;
  int rem = b & 31;
  int mat = rem >> 2, chunk = rem & 3;
  const size_t AS = 8ull * MS;
  size_t off = (size_t)mat * MS + (size_t)chunk * 65536;
  const ushort4* Ah = (const ushort4*)(U0 + (size_t)PA[pair] * AS + off);
  const ushort4* Al = (const ushort4*)(U0 + (size_t)(PA[pair] + 1) * AS + off);
  const ushort4* Bh = (const ushort4*)(U0 + (size_t)PB[pair] * AS + off);
  const ushort4* Bl = (const ushort4*)(U0 + (size_t)(PB[pair] + 1) * AS + off);
  float s = 0.0f;
  for (int i = threadIdx.x; i < 16384; i += 256) {
    ushort4 ah = Ah[i], al = Al[i], bh = Bh[i], bl = Bl[i];
    s += (b2f(ah.x) + b2f(al.x)) * (b2f(bh.x) + b2f(bl.x));
    s += (b2f(ah.y) + b2f(al.y)) * (b2f(bh.y) + b2f(bl.y));
    s += (b2f(ah.z) + b2f(al.z)) * (b2f(bh.z) + b2f(bl.z));
    s += (b2f(ah.w) + b2f(al.w)) * (b2f(bh.w) + b2f(bl.w));
  }
  for (int o = 32; o; o >>= 1) s += __shfl_down(s, o);
  __shared__ float red[4];
  if ((threadIdx.x & 63) == 0) red[threadIdx.x >> 6] = s;
  __syncthreads();
  if (threadIdx.x == 0)
    atomicAdd(&tau[pair * 8 + mat], red[0] + red[1] + red[2] + red[3]);
}

// ---------------- final scalar ----------------------------------------------
__global__ __launch_bounds__(256) void k_final(const float* __restrict__ trP,
                                               const float* __restrict__ covdiag,
                                               const float* __restrict__ means,
                                               B9 B, float* __restrict__ out) {
  float s = 0.0f;
  for (int i = threadIdx.x; i < 4096; i += 256) {
    float dm = means[i] - means[4096 + i];
    s += dm * dm;
  }
  for (int i = threadIdx.x; i < 8192; i += 256) s += covdiag[i];
  if (threadIdx.x < 8) {
    int m = threadIdx.x;
    float t1 = trP[m], t2 = trP[8 + m];
    float nu = NUSAFE * t2 / t1;
    float inv = 1.0f / nu;
    float tau[9];
    tau[0] = 512.0f;
    tau[1] = t1 * inv;
    float sc[7] = {inv * inv, inv, 1.f, 1.f, 1.f, 1.f, 1.f};
#pragma unroll
    for (int p = 0; p < 7; ++p) tau[p + 2] = trP[16 + p * 8 + m] * sc[p];
    float tp = 0.0f;
#pragma unroll
    for (int k = 0; k < 9; ++k) tp += B.v[k] * tau[k];
    s -= 2.0f * sqrtf(nu) * tp;
  }
  for (int o = 32; o; o >>= 1) s += __shfl_down(s, o);
  __shared__ float red[4];
  if ((threadIdx.x & 63) == 0) red[threadIdx.x >> 6] = s;
  __syncthreads();
  if (threadIdx.x == 0)
    out[0] = (red[0] + red[1] + red[2] + red[3]) * (1.0f / 4096.0f);
}

// ---------------- host: degree-8 Chebyshev fit of sqrt on [0.2,1.4] --------
static void fit_sqrt_coeffs(B9* out) {
  const int D = 8, N = 64;
  double a[D + 1];
  for (int n = 0; n <= D; ++n) {
    double s = 0.0;
    for (int m = 0; m < N; ++m) {
      double th = M_PI * (m + 0.5) / N;
      double x = 0.8 + 0.6 * cos(th);
      s += sqrt(x) * cos(n * th);
    }
    a[n] = 2.0 * s / N;
  }
  a[0] *= 0.5;
  double c[D + 1] = {0}, Tm[D + 1] = {0}, Tc[D + 1] = {0}, Tn[D + 1];
  Tm[0] = 1.0; c[0] += a[0];
  Tc[1] = 1.0; c[1] += a[1];
  for (int n = 2; n <= D; ++n) {
    for (int k = 0; k <= D; ++k) Tn[k] = -Tm[k];
    for (int k = 1; k <= D; ++k) Tn[k] += 2.0 * Tc[k - 1];
    for (int k = 0; k <= D; ++k) { c[k] += a[n] * Tn[k]; Tm[k] = Tc[k]; Tc[k] = Tn[k]; }
  }
  double b[D + 1] = {0};
  for (int k = 0; k <= D; ++k) {
    double inv6k = pow(1.0 / 0.6, k);
    double binom = 1.0;
    for (int jj = 0; jj <= k; ++jj) {
      b[jj] += c[k] * inv6k * binom * pow(-0.8, k - jj);
      binom = binom * (double)(k - jj) / (double)(jj + 1);
    }
  }
  for (int jj = 0; jj <= D; ++jj) out->v[jj] = (float)b[jj];
}

// ---------------- host ------------------------------------------------------
extern "C" void kernel_launch(void* const* d_in, const int* in_sizes, int n_in,
                              void* d_out, int out_size, void* d_ws, size_t ws_size,
                              hipStream_t stream) {
  (void)in_sizes; (void)n_in; (void)out_size; (void)ws_size;
  const float* X0 = (const float*)d_in[0];
  const float* X1 = (const float*)d_in[1];
  float* out = (float*)d_out;

  B9 B;
  fit_sqrt_coeffs(&B);

  char* w = (char*)d_ws;
  auto carve = [&](size_t bytes) -> void* {
    void* r = (void*)w;
    w += (bytes + 255) & ~(size_t)255;
    return r;
  };
  u16*   Xh   = (u16*)carve(2ull * 8 * 512 * 16384 * 2);  // 256 MiB
  float* covP = (float*)carve(4ull * 16 * MS * 4);        // 64 MiB = 16 units
  u16* Ch  = (u16*)carve(8 * MS * 2); u16* Cl  = (u16*)carve(8 * MS * 2);
  u16* TCh = (u16*)carve(8 * MS * 2); u16* TCl = (u16*)carve(8 * MS * 2);
  float* covdiag = (float*)carve(16 * 512 * 4);
  float* means = (float*)carve(8192 * 4);
  float* trP   = (float*)carve(128 * 4);  // tr1[8], fro2[8], tau[7][8]

  // Power arrays (4 MiB units) alias covP exactly (dead after covfin2).
  const size_t AS = 8ull * MS;
  u16* U0 = (u16*)covP;
  auto unit = [&](int i) -> u16* { return U0 + (size_t)i * AS; };
  u16 *U1h = unit(0), *U1l = unit(1), *U1th = unit(2), *U1tl = unit(3);
  u16 *U2h = unit(4), *U2l = unit(5), *U2th = unit(6), *U2tl = unit(7);
  u16 *U3h = unit(8), *U3l = unit(9), *U3th = unit(10), *U3tl = unit(11);
  u16 *U4h = unit(12), *U4l = unit(13), *U4th = unit(14), *U4tl = unit(15);

  // 1) fp32 -> bf16 + means
  k_convert<<<4096, 256, 0, stream>>>(X0, X1, Xh, means);

  // 2) SYRK (K-split 4) + fused finish/split (zeroes trP[0..71])
  k_syrk<<<640, 256, 0, stream>>>(Xh, covP);
  k_covfin2<<<2048, 256, 0, stream>>>(covP, means, covdiag, trP, Ch, Cl, TCh, TCl);

  // 3) U1 = G = C @ TC (TC symmetric) + moments (tr G, ||G||_F^2)
  {
    GJ gj = {Ch, Cl, TCh, TCl, U1h, U1l, U1th, U1tl,
             nullptr, trP, trP + 8, 1.0f, 0};
    k_gg<<<512, 256, 0, stream>>>(gj, gj, 512);
  }
  // 4) U2 = Ghat^2 = (G @ G) / nu^2
  {
    GJ pj = {U1h, U1l, U1th, U1tl, U2h, U2l, U2th, U2tl,
             trP, nullptr, nullptr, 1.0f, 2};
    k_gg<<<512, 256, 0, stream>>>(pj, pj, 512);
  }
  // 5) U3 = Ghat^3 = (Ghat^2 @ G)/nu ; U4 = Ghat^4 = Ghat^2 @ Ghat^2
  {
    GJ p3 = {U2h, U2l, U1th, U1tl, U3h, U3l, U3th, U3tl,
             trP, nullptr, nullptr, 1.0f, 1};
    GJ p4 = {U2h, U2l, U2th, U2tl, U4h, U4l, U4th, U4tl,
             trP, nullptr, nullptr, 1.0f, 0};
    k_gg<<<1024, 256, 0, stream>>>(p3, p4, 512);
  }
  // 6) transpose-dots -> tau_2..tau_8
  k_dots<<<224, 256, 0, stream>>>(U0, trP + 16);

  // 7) loss
  k_final<<<1, 256, 0, stream>>>(trP, covdiag, means, B, out);
}

// Round 13
// 409.652 us; speedup vs baseline: 1.7819x; 1.0613x over previous
//
#include <hip/hip_runtime.h>
#include <math.h>

// StyleLossW2 on MI355X. B=8, C=512, HW=16384. Output: 1 fp32 scalar.
// Round 13: SYRK back to SINGLE-buffered LDS core (32 KiB -> 5 blocks/CU,
// all 640 blocks co-resident, no scheduling tail; per-kstep drain hidden by
// TLP per m114). G-chain keeps double-buffered core. Everything else = r12.
// Power-trace polynomial for tr(sqrt(G)) (host-fit Chebyshev, deg 8).

typedef unsigned short u16;
typedef __bf16 bf16_t;
typedef bf16_t bf16x8 __attribute__((ext_vector_type(8)));
typedef float f32x4 __attribute__((ext_vector_type(4)));

#define EPSV 1e-4f
#define MS 262144   // 512*512
#define NUSAFE 1.35f

struct B9 { float v[9]; };

__device__ inline u16 f2b(float f) {
  bf16_t b = (bf16_t)f;
  return __builtin_bit_cast(u16, b);
}
__device__ inline float b2f(u16 u) {
  unsigned v = ((unsigned)u) << 16;
  return __builtin_bit_cast(float, v);
}

// ---------------- single-buffered MFMA tile core (SYRK: 32 KiB, 5 blk/CU) ---
template <int FRM, int FRN, int LDA, int LDB>
__device__ __forceinline__ void core1(const u16* A0, const u16* B0,
                                      int nsteps, u16* lds, f32x4 (&acc)[FRM][FRN],
                                      int wave, int lane) {
  const int TSA = FRM * 32 * 64;
  int rr = lane & 15, g4 = lane >> 4, wm = wave >> 1, wn = wave & 1;
  int swz = (rr & 7) << 3;
  for (int ks = 0; ks < nsteps; ++ks) {
    int k0 = ks * 64;
#pragma unroll
    for (int it = 0; it < FRM; ++it) {
      int chunk = it * 4 + wave;
      __builtin_amdgcn_global_load_lds(
          (const __attribute__((address_space(1))) unsigned int*)(A0 + (size_t)(chunk * 8) * LDA + k0),
          (__attribute__((address_space(3))) unsigned int*)&lds[chunk * 512], 16, 0, 0);
    }
#pragma unroll
    for (int it = 0; it < FRN; ++it) {
      int chunk = it * 4 + wave;
      __builtin_amdgcn_global_load_lds(
          (const __attribute__((address_space(1))) unsigned int*)(B0 + (size_t)(chunk * 8) * LDB + k0),
          (__attribute__((address_space(3))) unsigned int*)&lds[TSA + chunk * 512], 16, 0, 0);
    }
    __syncthreads();
#pragma unroll
    for (int kk = 0; kk < 2; ++kk) {
      int ko = (kk * 32 + g4 * 8) ^ swz;
      bf16x8 af[FRM], bv[FRN];
#pragma unroll
      for (int m = 0; m < FRM; ++m)
        af[m] = *(const bf16x8*)&lds[(wm * FRM * 16 + m * 16 + rr) * 64 + ko];
#pragma unroll
      for (int n = 0; n < FRN; ++n)
        bv[n] = *(const bf16x8*)&lds[TSA + (wn * FRN * 16 + n * 16 + rr) * 64 + ko];
#pragma unroll
      for (int m = 0; m < FRM; ++m)
#pragma unroll
        for (int n = 0; n < FRN; ++n)
          acc[m][n] = __builtin_amdgcn_mfma_f32_16x16x32_bf16(af[m], bv[n],
                                                              acc[m][n], 0, 0, 0);
    }
    __syncthreads();
  }
}

// ---------------- 2-phase double-buffered MFMA tile core (G-chain) ----------
template <int FRM, int FRN, int LDA, int LDB, int SPS>
__device__ __forceinline__ void core2(const u16* A0, const u16* A1, const u16* A2,
                                      const u16* B0, const u16* B1, const u16* B2,
                                      int nsteps, u16* lds, f32x4 (&acc)[FRM][FRN],
                                      int wave, int lane) {
  const int TSA = FRM * 32 * 64;
  const int TSB = FRN * 32 * 64;
  const u16* As[3] = {A0, A1, A2};
  const u16* Bs[3] = {B0, B1, B2};
  int rr = lane & 15, g4 = lane >> 4, wm = wave >> 1, wn = wave & 1;
  int swz = (rr & 7) << 3;
#pragma unroll
  for (int it = 0; it < FRM; ++it) {
    int chunk = it * 4 + wave;
    __builtin_amdgcn_global_load_lds(
        (const __attribute__((address_space(1))) unsigned int*)(A0 + (size_t)(chunk * 8) * LDA),
        (__attribute__((address_space(3))) unsigned int*)&lds[chunk * 512], 16, 0, 0);
  }
#pragma unroll
  for (int it = 0; it < FRN; ++it) {
    int chunk = it * 4 + wave;
    __builtin_amdgcn_global_load_lds(
        (const __attribute__((address_space(1))) unsigned int*)(B0 + (size_t)(chunk * 8) * LDB),
        (__attribute__((address_space(3))) unsigned int*)&lds[TSA + chunk * 512], 16, 0, 0);
  }
  __syncthreads();
  int buf = 0;
  for (int ks = 0; ks < nsteps; ++ks) {
    if (ks + 1 < nsteps) {
      int kn = ks + 1;
      int seg = kn / SPS;
      int k0 = (kn % SPS) * 64;
      const u16* A = As[seg];
      const u16* B = Bs[seg];
      u16* dst = lds + (buf ^ 1) * (TSA + TSB);
#pragma unroll
      for (int it = 0; it < FRM; ++it) {
        int chunk = it * 4 + wave;
        __builtin_amdgcn_global_load_lds(
            (const __attribute__((address_space(1))) unsigned int*)(A + (size_t)(chunk * 8) * LDA + k0),
            (__attribute__((address_space(3))) unsigned int*)&dst[chunk * 512], 16, 0, 0);
      }
#pragma unroll
      for (int it = 0; it < FRN; ++it) {
        int chunk = it * 4 + wave;
        __builtin_amdgcn_global_load_lds(
            (const __attribute__((address_space(1))) unsigned int*)(B + (size_t)(chunk * 8) * LDB + k0),
            (__attribute__((address_space(3))) unsigned int*)&dst[TSA + chunk * 512], 16, 0, 0);
      }
    }
    const u16* lb = lds + buf * (TSA + TSB);
#pragma unroll
    for (int kk = 0; kk < 2; ++kk) {
      int ko = (kk * 32 + g4 * 8) ^ swz;
      bf16x8 af[FRM], bv[FRN];
#pragma unroll
      for (int m = 0; m < FRM; ++m)
        af[m] = *(const bf16x8*)&lb[(wm * FRM * 16 + m * 16 + rr) * 64 + ko];
#pragma unroll
      for (int n = 0; n < FRN; ++n)
        bv[n] = *(const bf16x8*)&lb[TSA + (wn * FRN * 16 + n * 16 + rr) * 64 + ko];
#pragma unroll
      for (int m = 0; m < FRM; ++m)
#pragma unroll
        for (int n = 0; n < FRN; ++n)
          acc[m][n] = __builtin_amdgcn_mfma_f32_16x16x32_bf16(af[m], bv[n],
                                                              acc[m][n], 0, 0, 0);
    }
    __syncthreads();
    buf ^= 1;
  }
}

// ---------------- convert fp32 -> bf16, 4-deep batched loads ----------------
__global__ __launch_bounds__(256) void k_convert(const float* __restrict__ X0,
                                                 const float* __restrict__ X1,
                                                 u16* __restrict__ Xh,
                                                 float* __restrict__ means) {
  int wave = threadIdx.x >> 6, lane = threadIdx.x & 63;
  int r = blockIdx.x * 2 + (wave >> 1);   // 4096 blocks -> 8192 rows
  int half = wave & 1;
  const float* src = (r < 4096) ? X0 : X1;
  size_t off = (size_t)(r & 4095) * 16384 + half * 8192;
  const f32x4* s4 = (const f32x4*)(src + off);
  uint4* dst = (uint4*)(Xh + (size_t)r * 16384 + half * 8192);
  float sum = 0.0f;
#pragma unroll 2
  for (int i = 0; i < 8; ++i) {
    int c0 = (i * 2) * 64 + lane;
    int c1 = c0 + 64;
    f32x4 a0 = s4[2 * c0], b0 = s4[2 * c0 + 1];
    f32x4 a1 = s4[2 * c1], b1 = s4[2 * c1 + 1];
    sum += a0.x + a0.y + a0.z + a0.w + b0.x + b0.y + b0.z + b0.w;
    sum += a1.x + a1.y + a1.z + a1.w + b1.x + b1.y + b1.z + b1.w;
    uint4 o0, o1;
    o0.x = (unsigned)f2b(a0.x) | ((unsigned)f2b(a0.y) << 16);
    o0.y = (unsigned)f2b(a0.z) | ((unsigned)f2b(a0.w) << 16);
    o0.z = (unsigned)f2b(b0.x) | ((unsigned)f2b(b0.y) << 16);
    o0.w = (unsigned)f2b(b0.z) | ((unsigned)f2b(b0.w) << 16);
    o1.x = (unsigned)f2b(a1.x) | ((unsigned)f2b(a1.y) << 16);
    o1.y = (unsigned)f2b(a1.z) | ((unsigned)f2b(a1.w) << 16);
    o1.z = (unsigned)f2b(b1.x) | ((unsigned)f2b(b1.y) << 16);
    o1.w = (unsigned)f2b(b1.z) | ((unsigned)f2b(b1.w) << 16);
    dst[c0] = o0;
    dst[c1] = o1;
  }
  for (int o = 32; o; o >>= 1) sum += __shfl_down(sum, o);
  __shared__ float red[4];
  if (lane == 0) red[wave] = sum;
  __syncthreads();
  if (threadIdx.x == 0) {
    means[blockIdx.x * 2] = (red[0] + red[1]) * (1.0f / 16384.0f);
    means[blockIdx.x * 2 + 1] = (red[2] + red[3]) * (1.0f / 16384.0f);
  }
}

// ---------------- SYRK: 640 jobs = 16 mats x 10 sym-tiles x 4 K-quarters ----
// single-buffered core: 32 KiB LDS -> 5 blocks/CU -> all 640 co-resident
__global__ __launch_bounds__(256) void k_syrk(const u16* __restrict__ Xh,
                                              float* __restrict__ covP) {
  const int TIv[10] = {0, 0, 0, 0, 1, 1, 1, 2, 2, 3};
  const int TJv[10] = {0, 1, 2, 3, 1, 2, 3, 2, 3, 3};
  int b = blockIdx.x;
  int sid = (b & 7) * 80 + (b >> 3);  // bijective XCD swizzle
  int mat = sid / 40, rem = sid % 40;
  int t = rem >> 2, q = rem & 3;
  int ti = TIv[t], tj = TJv[t];
  int tid = threadIdx.x, wave = tid >> 6, lane = tid & 63;
  __shared__ u16 lds[2 * 128 * 64];  // 32 KiB (single-buffered)
  f32x4 acc[4][4] = {};
  int srow = lane >> 3;
  int scol = ((lane & 7) * 8) ^ (srow << 3);
  const u16* base = Xh + (size_t)mat * 512 * 16384 + (size_t)q * 4096;
  const u16* Ab = base + (size_t)(ti * 128 + srow) * 16384 + scol;
  const u16* Bb = base + (size_t)(tj * 128 + srow) * 16384 + scol;
  core1<4, 4, 16384, 16384>(Ab, Bb, 64, lds, acc, wave, lane);
  int wm = wave >> 1, wn = wave & 1, rr = lane & 15, g4 = lane >> 4;
  float* out = covP + ((size_t)q * 16 + mat) * MS;
#pragma unroll
  for (int m = 0; m < 4; ++m)
#pragma unroll
    for (int n = 0; n < 4; ++n) {
      int rowb = ti * 128 + wm * 64 + m * 16 + g4 * 4;
      int col = tj * 128 + wn * 64 + n * 16 + rr;
      float v0 = acc[m][n][0], v1 = acc[m][n][1], v2 = acc[m][n][2], v3 = acc[m][n][3];
      out[(size_t)(rowb + 0) * 512 + col] = v0;
      out[(size_t)(rowb + 1) * 512 + col] = v1;
      out[(size_t)(rowb + 2) * 512 + col] = v2;
      out[(size_t)(rowb + 3) * 512 + col] = v3;
      if (ti != tj) {
        float4 tv = {v0, v1, v2, v3};
        *(float4*)&out[(size_t)col * 512 + rowb] = tv;
      }
    }
}

// ---- cov finish: sum 4 K-quarters, /HW - mean outer + eps I ->
//      hi/lo bf16 (C 0-7, TC 8-15) + fp32 diag; zero trP[0..71] -------------
__global__ __launch_bounds__(256) void k_covfin2(const float* __restrict__ covP,
                                                 const float* __restrict__ means,
                                                 float* __restrict__ covdiag,
                                                 float* __restrict__ trP,
                                                 u16* __restrict__ Ch, u16* __restrict__ Cl,
                                                 u16* __restrict__ TCh, u16* __restrict__ TCl) {
  if (blockIdx.x == 0 && threadIdx.x < 72) trP[threadIdx.x] = 0.0f;
  const int NF4 = 16 * MS / 4;
  const float4* P = (const float4*)covP;
  for (int i4 = blockIdx.x * 256 + threadIdx.x; i4 < NF4; i4 += gridDim.x * 256) {
    float4 v0 = P[i4];
    float v[4] = {v0.x, v0.y, v0.z, v0.w};
#pragma unroll
    for (int k = 1; k < 4; ++k) {
      float4 a = P[(size_t)k * NF4 + i4];
      v[0] += a.x; v[1] += a.y; v[2] += a.z; v[3] += a.w;
    }
    int mat = i4 >> 16;
    int r = (i4 >> 7) & 511;
    int cb = (i4 & 127) * 4;
    float mr = means[mat * 512 + r];
    ushort4 h4, l4;
    unsigned short* ph = &h4.x;
    unsigned short* pl = &l4.x;
#pragma unroll
    for (int t = 0; t < 4; ++t) {
      float vv = v[t] * (1.0f / 16384.0f) - mr * means[mat * 512 + cb + t];
      if (r == cb + t) {
        vv += EPSV;
        covdiag[mat * 512 + r] = vv;
      }
      u16 hh = f2b(vv);
      ph[t] = hh;
      pl[t] = f2b(vv - b2f(hh));
    }
    int half = (mat >= 8);
    int loc4 = i4 - half * (NF4 / 2);
    ((ushort4*)(half ? TCh : Ch))[loc4] = h4;
    ((ushort4*)(half ? TCl : Cl))[loc4] = l4;
  }
}

// ---------------- power GEMM, 64x64 tiles -----------------------------------
struct GJ {
  const u16 *Ah, *Al, *Bh, *Bl;   // B arrays are transposed-layout operands
  u16 *oH, *oL, *oTH, *oTL;
  const float* trP;
  float* tr1A; float* tr2A;
  float c0;
  int nupow;
};

__global__ __launch_bounds__(256) void k_gg(GJ p, GJ q, int split) {
  int sid = ((blockIdx.x & 7) * (gridDim.x >> 3)) + (blockIdx.x >> 3);
  const GJ j = (sid < split) ? p : q;
  int blk = (sid < split) ? sid : sid - split;
  int mat = blk >> 6, tile = blk & 63;
  int ti = tile >> 3, tj = tile & 7;
  int tid = threadIdx.x, wave = tid >> 6, lane = tid & 63;
  __shared__ u16 lds[2 * 2 * 64 * 64];  // 32 KB
  f32x4 acc[2][2] = {};
  int srow = lane >> 3;
  int scol = ((lane & 7) * 8) ^ (srow << 3);
  size_t mo = (size_t)mat * MS;
  size_t ao = mo + (size_t)(ti * 64 + srow) * 512 + scol;
  size_t bo = mo + (size_t)(tj * 64 + srow) * 512 + scol;
  const u16* A0 = j.Ah + ao;
  const u16* A2 = j.Al + ao;
  const u16* B0 = j.Bh + bo;
  const u16* B1 = j.Bl + bo;
  core2<2, 2, 512, 512, 8>(A0, A0, A2, B0, B1, B0, 24, lds, acc, wave, lane);
  int wm = wave >> 1, wn = wave & 1, rr = lane & 15, g4 = lane >> 4;
  float c0 = j.c0;
  if (j.nupow) {
    float inv = j.trP[mat] / (NUSAFE * j.trP[8 + mat]);  // 1/nu
    c0 *= inv;
    if (j.nupow == 2) c0 *= inv;
  }
  float fro = 0.0f, dsum = 0.0f;
#pragma unroll
  for (int m = 0; m < 2; ++m)
#pragma unroll
    for (int n = 0; n < 2; ++n) {
      int rowb = ti * 64 + wm * 32 + m * 16 + g4 * 4;
      int col = tj * 64 + wn * 32 + n * 16 + rr;
      ushort4 h4, l4;
      unsigned short* ph = &h4.x;
      unsigned short* pl = &l4.x;
#pragma unroll
      for (int v4 = 0; v4 < 4; ++v4) {
        float vv = c0 * acc[m][n][v4];
        u16 hh = f2b(vv);
        ph[v4] = hh;
        pl[v4] = f2b(vv - b2f(hh));
        if (j.tr2A) {
          fro += vv * vv;
          if ((rowb + v4) == col) dsum += vv;
        }
        j.oH[mo + (size_t)(rowb + v4) * 512 + col] = hh;
        j.oL[mo + (size_t)(rowb + v4) * 512 + col] = pl[v4];
      }
      *(ushort4*)&j.oTH[mo + (size_t)col * 512 + rowb] = h4;
      *(ushort4*)&j.oTL[mo + (size_t)col * 512 + rowb] = l4;
    }
  if (j.tr2A) {
    for (int o = 32; o; o >>= 1) {
      fro += __shfl_down(fro, o);
      dsum += __shfl_down(dsum, o);
    }
    if (lane == 0) {
      atomicAdd(&j.tr2A[mat], fro);
      if (ti == tj) atomicAdd(&j.tr1A[mat], dsum);
    }
  }
}

// ---------------- transpose-dots: tau_{p+2} = <A_p, B_p^T> ------------------
__global__ __launch_bounds__(256) void k_dots(const u16* __restrict__ U0,
                                              float* __restrict__ tau) {
  const int PA[7] = {0, 4, 4, 8, 8, 12, 12};
  const int PB[7] = {2, 2, 6, 6, 10, 10, 14};
  int b = blockIdx.x;           // 224 = 7 pairs x 8 mats x 4 chunks
  int pair = b / 32;
  int rem = b & 31;
  int mat = rem >> 2, chunk = rem & 3;
  const size_t AS = 8ull * MS;
  size_t off = (size_t)mat * MS + (size_t)chunk * 65536;
  const ushort4* Ah = (const ushort4*)(U0 + (size_t)PA[pair] * AS + off);
  const ushort4* Al = (const ushort4*)(U0 + (size_t)(PA[pair] + 1) * AS + off);
  const ushort4* Bh = (const ushort4*)(U0 + (size_t)PB[pair] * AS + off);
  const ushort4* Bl = (const ushort4*)(U0 + (size_t)(PB[pair] + 1) * AS + off);
  float s = 0.0f;
  for (int i = threadIdx.x; i < 16384; i += 256) {
    ushort4 ah = Ah[i], al = Al[i], bh = Bh[i], bl = Bl[i];
    s += (b2f(ah.x) + b2f(al.x)) * (b2f(bh.x) + b2f(bl.x));
    s += (b2f(ah.y) + b2f(al.y)) * (b2f(bh.y) + b2f(bl.y));
    s += (b2f(ah.z) + b2f(al.z)) * (b2f(bh.z) + b2f(bl.z));
    s += (b2f(ah.w) + b2f(al.w)) * (b2f(bh.w) + b2f(bl.w));
  }
  for (int o = 32; o; o >>= 1) s += __shfl_down(s, o);
  __shared__ float red[4];
  if ((threadIdx.x & 63) == 0) red[threadIdx.x >> 6] = s;
  __syncthreads();
  if (threadIdx.x == 0)
    atomicAdd(&tau[pair * 8 + mat], red[0] + red[1] + red[2] + red[3]);
}

// ---------------- final scalar ----------------------------------------------
__global__ __launch_bounds__(256) void k_final(const float* __restrict__ trP,
                                               const float* __restrict__ covdiag,
                                               const float* __restrict__ means,
                                               B9 B, float* __restrict__ out) {
  float s = 0.0f;
  for (int i = threadIdx.x; i < 4096; i += 256) {
    float dm = means[i] - means[4096 + i];
    s += dm * dm;
  }
  for (int i = threadIdx.x; i < 8192; i += 256) s += covdiag[i];
  if (threadIdx.x < 8) {
    int m = threadIdx.x;
    float t1 = trP[m], t2 = trP[8 + m];
    float nu = NUSAFE * t2 / t1;
    float inv = 1.0f / nu;
    float tau[9];
    tau[0] = 512.0f;
    tau[1] = t1 * inv;
    float sc[7] = {inv * inv, inv, 1.f, 1.f, 1.f, 1.f, 1.f};
#pragma unroll
    for (int p = 0; p < 7; ++p) tau[p + 2] = trP[16 + p * 8 + m] * sc[p];
    float tp = 0.0f;
#pragma unroll
    for (int k = 0; k < 9; ++k) tp += B.v[k] * tau[k];
    s -= 2.0f * sqrtf(nu) * tp;
  }
  for (int o = 32; o; o >>= 1) s += __shfl_down(s, o);
  __shared__ float red[4];
  if ((threadIdx.x & 63) == 0) red[threadIdx.x >> 6] = s;
  __syncthreads();
  if (threadIdx.x == 0)
    out[0] = (red[0] + red[1] + red[2] + red[3]) * (1.0f / 4096.0f);
}

// ---------------- host: degree-8 Chebyshev fit of sqrt on [0.2,1.4] --------
static void fit_sqrt_coeffs(B9* out) {
  const int D = 8, N = 64;
  double a[D + 1];
  for (int n = 0; n <= D; ++n) {
    double s = 0.0;
    for (int m = 0; m < N; ++m) {
      double th = M_PI * (m + 0.5) / N;
      double x = 0.8 + 0.6 * cos(th);
      s += sqrt(x) * cos(n * th);
    }
    a[n] = 2.0 * s / N;
  }
  a[0] *= 0.5;
  double c[D + 1] = {0}, Tm[D + 1] = {0}, Tc[D + 1] = {0}, Tn[D + 1];
  Tm[0] = 1.0; c[0] += a[0];
  Tc[1] = 1.0; c[1] += a[1];
  for (int n = 2; n <= D; ++n) {
    for (int k = 0; k <= D; ++k) Tn[k] = -Tm[k];
    for (int k = 1; k <= D; ++k) Tn[k] += 2.0 * Tc[k - 1];
    for (int k = 0; k <= D; ++k) { c[k] += a[n] * Tn[k]; Tm[k] = Tc[k]; Tc[k] = Tn[k]; }
  }
  double b[D + 1] = {0};
  for (int k = 0; k <= D; ++k) {
    double inv6k = pow(1.0 / 0.6, k);
    double binom = 1.0;
    for (int jj = 0; jj <= k; ++jj) {
      b[jj] += c[k] * inv6k * binom * pow(-0.8, k - jj);
      binom = binom * (double)(k - jj) / (double)(jj + 1);
    }
  }
  for (int jj = 0; jj <= D; ++jj) out->v[jj] = (float)b[jj];
}

// ---------------- host ------------------------------------------------------
extern "C" void kernel_launch(void* const* d_in, const int* in_sizes, int n_in,
                              void* d_out, int out_size, void* d_ws, size_t ws_size,
                              hipStream_t stream) {
  (void)in_sizes; (void)n_in; (void)out_size; (void)ws_size;
  const float* X0 = (const float*)d_in[0];
  const float* X1 = (const float*)d_in[1];
  float* out = (float*)d_out;

  B9 B;
  fit_sqrt_coeffs(&B);

  char* w = (char*)d_ws;
  auto carve = [&](size_t bytes) -> void* {
    void* r = (void*)w;
    w += (bytes + 255) & ~(size_t)255;
    return r;
  };
  u16*   Xh   = (u16*)carve(2ull * 8 * 512 * 16384 * 2);  // 256 MiB
  float* covP = (float*)carve(4ull * 16 * MS * 4);        // 64 MiB = 16 units
  u16* Ch  = (u16*)carve(8 * MS * 2); u16* Cl  = (u16*)carve(8 * MS * 2);
  u16* TCh = (u16*)carve(8 * MS * 2); u16* TCl = (u16*)carve(8 * MS * 2);
  float* covdiag = (float*)carve(16 * 512 * 4);
  float* means = (float*)carve(8192 * 4);
  float* trP   = (float*)carve(128 * 4);  // tr1[8], fro2[8], tau[7][8]

  // Power arrays (4 MiB units) alias covP exactly (dead after covfin2).
  const size_t AS = 8ull * MS;
  u16* U0 = (u16*)covP;
  auto unit = [&](int i) -> u16* { return U0 + (size_t)i * AS; };
  u16 *U1h = unit(0), *U1l = unit(1), *U1th = unit(2), *U1tl = unit(3);
  u16 *U2h = unit(4), *U2l = unit(5), *U2th = unit(6), *U2tl = unit(7);
  u16 *U3h = unit(8), *U3l = unit(9), *U3th = unit(10), *U3tl = unit(11);
  u16 *U4h = unit(12), *U4l = unit(13), *U4th = unit(14), *U4tl = unit(15);

  // 1) fp32 -> bf16 + means
  k_convert<<<4096, 256, 0, stream>>>(X0, X1, Xh, means);

  // 2) SYRK (K-split 4, single-buffered, all blocks co-resident) + finish
  k_syrk<<<640, 256, 0, stream>>>(Xh, covP);
  k_covfin2<<<2048, 256, 0, stream>>>(covP, means, covdiag, trP, Ch, Cl, TCh, TCl);

  // 3) U1 = G = C @ TC (TC symmetric) + moments (tr G, ||G||_F^2)
  {
    GJ gj = {Ch, Cl, TCh, TCl, U1h, U1l, U1th, U1tl,
             nullptr, trP, trP + 8, 1.0f, 0};
    k_gg<<<512, 256, 0, stream>>>(gj, gj, 512);
  }
  // 4) U2 = Ghat^2 = (G @ G) / nu^2
  {
    GJ pj = {U1h, U1l, U1th, U1tl, U2h, U2l, U2th, U2tl,
             trP, nullptr, nullptr, 1.0f, 2};
    k_gg<<<512, 256, 0, stream>>>(pj, pj, 512);
  }
  // 5) U3 = Ghat^3 = (Ghat^2 @ G)/nu ; U4 = Ghat^4 = Ghat^2 @ Ghat^2
  {
    GJ p3 = {U2h, U2l, U1th, U1tl, U3h, U3l, U3th, U3tl,
             trP, nullptr, nullptr, 1.0f, 1};
    GJ p4 = {U2h, U2l, U2th, U2tl, U4h, U4l, U4th, U4tl,
             trP, nullptr, nullptr, 1.0f, 0};
    k_gg<<<1024, 256, 0, stream>>>(p3, p4, 512);
  }
  // 6) transpose-dots -> tau_2..tau_8
  k_dots<<<224, 256, 0, stream>>>(U0, trP + 16);

  // 7) loss
  k_final<<<1, 256, 0, stream>>>(trP, covdiag, means, B, out);
}